// Round 16
// baseline (283.459 us; speedup 1.0000x reference)
//
#include <hip/hip_runtime.h>
#include <hip/hip_bf16.h>

// Problem constants
#define Bc 2
#define Tc 2048
#define Cc 2048
#define Hc 16
#define Dc 128
#define BTc 4096
#define NQ 6144            // 3*Cc
#define EPSc 1e-5f
#define QSCALE 0.08838834764831845f   // 1/sqrt(128)

typedef __attribute__((ext_vector_type(8))) short bf16x8;
typedef __attribute__((ext_vector_type(4))) short bf16x4;
typedef __attribute__((ext_vector_type(4))) float f32x4;

typedef struct { unsigned short u[4]; } us4;

__device__ __forceinline__ f32x4 mfma16(bf16x8 a, bf16x8 b, f32x4 c) {
  return __builtin_amdgcn_mfma_f32_16x16x32_bf16(a, b, c, 0, 0, 0);
}

__device__ __forceinline__ void gload16(const void* g, void* l) {
  __builtin_amdgcn_global_load_lds(
      (const __attribute__((address_space(1))) void*)g,
      (__attribute__((address_space(3))) void*)l, 16, 0, 0);
}

// ---------------- fp32 -> bf16 convert (x) ----------------
__global__ __launch_bounds__(256) void k_xconv(const float* __restrict__ x,
                                               __hip_bfloat16* __restrict__ xb) {
  size_t i = ((size_t)blockIdx.x * 256 + threadIdx.x) * 4;
  float4 v = *(const float4*)(x + i);
  union { __hip_bfloat16 h[4]; bf16x4 v4; } u;
  u.h[0] = __float2bfloat16(v.x); u.h[1] = __float2bfloat16(v.y);
  u.h[2] = __float2bfloat16(v.z); u.h[3] = __float2bfloat16(v.w);
  *(bf16x4*)(xb + i) = u.v4;
}

// ------- weight transpose+convert: W (K x N) fp32 -> Wt (N x K) bf16 -------
__global__ __launch_bounds__(256) void k_wconv(const float* __restrict__ Wq,
    const float* __restrict__ Wk, const float* __restrict__ Wv,
    const float* __restrict__ Wp, __hip_bfloat16* __restrict__ Wqkv_t,
    __hip_bfloat16* __restrict__ Wproj_t) {
  __shared__ float tile[64][65];
  int z = blockIdx.z;
  const float* src = (z == 0) ? Wq : (z == 1) ? Wk : (z == 2) ? Wv : Wp;
  __hip_bfloat16* dst = (z < 3) ? (Wqkv_t + (size_t)z * Cc * Cc) : Wproj_t;
  int k0 = blockIdx.x * 64, n0 = blockIdx.y * 64;
  int l16 = threadIdx.x & 15, rg = threadIdx.x >> 4;   // 16 lanes/row, 16 rows
#pragma unroll
  for (int p = 0; p < 4; p++) {
    int r = p * 16 + rg;
    float4 v = *(const float4*)(src + (size_t)(k0 + r) * Cc + n0 + l16 * 4);
    tile[r][l16 * 4 + 0] = v.x; tile[r][l16 * 4 + 1] = v.y;
    tile[r][l16 * 4 + 2] = v.z; tile[r][l16 * 4 + 3] = v.w;
  }
  __syncthreads();
#pragma unroll
  for (int p = 0; p < 4; p++) {
    int rn = p * 16 + rg;
    int ck = l16 * 4;
    union { us4 s; unsigned long long q; } u;
#pragma unroll
    for (int j = 0; j < 4; j++) {
      union { __hip_bfloat16 h; unsigned short v; } cv;
      cv.h = __float2bfloat16(tile[ck + j][rn]);
      u.s.u[j] = cv.v;
    }
    *(unsigned long long*)(dst + (size_t)(n0 + rn) * Cc + k0 + ck) = u.q;
  }
}

// ====== 128x128-tile GEMM, 4 waves of 32x128, BK=32, ring-3, 3 blocks/CU ===
// Occupancy lever: 48KB LDS ring (3 x 16KB) + launch_bounds(256,3) ->
// 3 blocks/CU = 12 waves = 3/SIMD (was 2/SIMD) to cover barrier/LDS stalls.
// Per phase: 10 ds_read_b128 + 4 gload16 + 16 MFMA + vmcnt(4) + 1 barrier.
// Buf layout (16KB): A 128rows x 32k @0 (8KB), B 128cols x 32k @8192.
// Rows of 64B, 16B-chunk XOR swizzle chunk^=((row>>1)&3) (pre-swizzled
// global source; gload dest linear in tid: dst=BUF+tid*16).
// Tile t reads buf t%3, stages t+2 into (t+2)%3 (read-drained at t-1's
// barrier since MFMA consumes reads before each wave's barrier).
// MODE 0: plain out.  MODE 1 (QKV fused, by-region by>>4): 0=Q rmsnorm*qw
// *QSCALE, 1=K rmsnorm*kw, 2=V transposed to Vt (wave owns full 128-col head).
__device__ __forceinline__ void mm28(f32x4 (&acc)[2][8], const bf16x8 (&A_)[2],
                                     const bf16x8 (&B_)[8]) {
  __builtin_amdgcn_s_setprio(1);
#pragma unroll
  for (int m = 0; m < 2; m++)
#pragma unroll
    for (int n = 0; n < 8; n++)
      acc[m][n] = mfma16(A_[m], B_[n], acc[m][n]);
  __builtin_amdgcn_s_setprio(0);
}

template <int MODE, typename OutT>
__global__ __launch_bounds__(256, 3) void k_gemmf(const __hip_bfloat16* __restrict__ A,
    const __hip_bfloat16* __restrict__ Bt, OutT* __restrict__ Co,
    int M, int N, const float* __restrict__ qw, const float* __restrict__ kw,
    __hip_bfloat16* __restrict__ Vt) {
  constexpr int K = 2048;
  __shared__ __align__(16) char lds[49152];            // 3 x 16KB ring
  const int nbx = M >> 7;                               // 128-row tiles
  const int nwg = nbx * (N >> 7);                       // %8==0
  const int wg = blockIdx.x;
  const int swz = (wg & 7) * (nwg >> 3) + (wg >> 3);
  const int bx = swz % nbx, by = swz / nbx;
  const int tid = threadIdx.x, lane = tid & 63, wid = tid >> 6;
  const int lr = lane & 15, lg = lane >> 4;
  const int xs = lg ^ ((lr >> 1) & 3);
  const int aoffR = (wid * 32 + lr) * 64 + xs * 16;     // + m*1024 + buf
  const int boffR = 8192 + lr * 64 + xs * 16;           // + n*1024 + buf
  // staging: thread covers rows (tid>>2) and (tid>>2)+64, chunk pre-swizzled
  const int srow = tid >> 2;
  const int scolE = (((tid & 3) ^ ((tid >> 3) & 3)) << 3);
  const __hip_bfloat16* Ag = A + (size_t)(bx * 128 + srow) * K + scolE;
  const __hip_bfloat16* Bg = Bt + (size_t)(by * 128 + srow) * K + scolE;
  const size_t r64K = (size_t)64 * K;
  char* dA = lds + wid * 1024;          // + BUF (+4096 for j=1)
  char* dB = lds + 8192 + wid * 1024;   // + BUF (+4096 for j=1)

#define STG(BUF, TS) {                                                   \
    gload16(Ag + (TS) * 32,        dA + (BUF));                          \
    gload16(Ag + r64K + (TS) * 32, dA + (BUF) + 4096);                   \
    gload16(Bg + (TS) * 32,        dB + (BUF));                          \
    gload16(Bg + r64K + (TS) * 32, dB + (BUF) + 4096);                   \
  }
#define BARRIER asm volatile("s_barrier" ::: "memory")
#define VW4 asm volatile("s_waitcnt vmcnt(4)" ::: "memory")
#define VW0 asm volatile("s_waitcnt vmcnt(0)" ::: "memory")

  f32x4 acc[2][8];
#pragma unroll
  for (int m = 0; m < 2; m++)
#pragma unroll
    for (int n = 0; n < 8; n++) acc[m][n] = f32x4{0.f, 0.f, 0.f, 0.f};
  bf16x8 rA[2], rB[8];

#define PH(RB, SB, TS, DOSTG, ENDW) {                                    \
    _Pragma("unroll")                                                    \
    for (int m = 0; m < 2; m++)                                          \
      rA[m] = *(const bf16x8*)(lds + (RB) * 16384 + aoffR + m * 1024);   \
    _Pragma("unroll")                                                    \
    for (int n = 0; n < 8; n++)                                          \
      rB[n] = *(const bf16x8*)(lds + (RB) * 16384 + boffR + n * 1024);   \
    if (DOSTG) STG((SB) * 16384, (TS));                                  \
    mm28(acc, rA, rB);                                                   \
    ENDW;                                                                \
    BARRIER;                                                             \
  }

  // prologue: stage tiles 0,1 into bufs 0,1; tile0 landed at VW4
  STG(0, 0); STG(16384, 1);
  VW4;
  BARRIER;

  for (int i = 0; i < 20; ++i) {
    const int t = 3 * i;
    PH(0, 2, t + 2, 1, VW4);    // tile 3i
    PH(1, 0, t + 3, 1, VW4);    // tile 3i+1
    PH(2, 1, t + 4, 1, VW4);    // tile 3i+2
  }
  PH(0, 2, 62, 1, VW4);         // t=60
  PH(1, 0, 63, 1, VW4);         // t=61
  PH(2, 0, 0, 0, VW0);          // t=62 (drain tile 63's stage)
  PH(0, 0, 0, 0, (void)0);      // t=63
#undef PH
#undef STG
#undef BARRIER
#undef VW4
#undef VW0

  const int row0 = bx * 128 + wid * 32 + lg * 4;
  const int col0 = by * 128 + lr;

  if (MODE == 1) {
    const int region = by >> 4;            // 0=Q, 1=K, 2=V
    const int h = by & 15;
    if (region < 2) {
      const float* wsel = (region == 0) ? qw : kw;
      const float extra = (region == 0) ? QSCALE : 1.0f;
      float wv[8];
#pragma unroll
      for (int n = 0; n < 8; n++) wv[n] = wsel[n * 16 + lr];
#pragma unroll
      for (int m = 0; m < 2; m++) {
        float ss[4] = {0.f, 0.f, 0.f, 0.f};
#pragma unroll
        for (int n = 0; n < 8; n++)
#pragma unroll
          for (int r = 0; r < 4; r++) ss[r] += acc[m][n][r] * acc[m][n][r];
        for (int msk = 1; msk < 16; msk <<= 1)
#pragma unroll
          for (int r = 0; r < 4; r++) ss[r] += __shfl_xor(ss[r], msk);
        float sc[4];
#pragma unroll
        for (int r = 0; r < 4; r++)
          sc[r] = rsqrtf(ss[r] * (1.0f / Dc) + EPSc) * extra;
#pragma unroll
        for (int n = 0; n < 8; n++) {
          size_t base = (size_t)(row0 + m * 16) * N + col0 + n * 16;
#pragma unroll
          for (int r = 0; r < 4; r++)
            ((__hip_bfloat16*)Co)[base + (size_t)r * N] =
                __float2bfloat16(acc[m][n][r] * sc[r] * wv[n]);
        }
      }
    } else {
      // V: write transposed to Vt[(b*16+h)*128 + d][t]
      const int bat = bx >> 4;                            // batch (rows/2048)
#pragma unroll
      for (int m = 0; m < 2; m++) {
        const int t0 = (row0 + m * 16) & (Tc - 1);
#pragma unroll
        for (int n = 0; n < 8; n++) {
          union { us4 p; unsigned long long q; } u;
#pragma unroll
          for (int r = 0; r < 4; r++) {
            union { __hip_bfloat16 h16; unsigned short s; } cv;
            cv.h16 = __float2bfloat16(acc[m][n][r]);
            u.p.u[r] = cv.s;
          }
          __hip_bfloat16* dst = Vt +
              ((size_t)(bat * 16 + h) * 128 + n * 16 + lr) * Tc + t0;
          *(unsigned long long*)dst = u.q;
        }
      }
    }
  } else {
#pragma unroll
    for (int m = 0; m < 2; m++)
#pragma unroll
      for (int n = 0; n < 8; n++) {
        size_t base = (size_t)(row0 + m * 16) * N + col0 + n * 16;
#pragma unroll
        for (int r = 0; r < 4; r++) {
          float v = acc[m][n][r];
          if constexpr (sizeof(OutT) == 2)
            Co[base + (size_t)r * N] = __float2bfloat16(v);
          else
            Co[base + (size_t)r * N] = v;
        }
      }
  }
}

// ---------------- flash attention: counted-vmcnt pipeline, r7 softmax ------
// + deferred l-sum (epilogue reduce) + full-chunk fast path (both verified).
__global__ __launch_bounds__(256, 2) void k_attn(const __hip_bfloat16* __restrict__ QKV,
    const __hip_bfloat16* __restrict__ Vt, const float* __restrict__ subw,
    __hip_bfloat16* __restrict__ Y) {
  __shared__ __align__(16) __hip_bfloat16 Ks[2][64][128];   // 32 KB
  __shared__ __align__(16) __hip_bfloat16 Vs[2][128][64];   // 32 KB
  __shared__ __align__(16) __hip_bfloat16 Plds[4][16][72];  // 9 KB
  const int bh = blockIdx.x, pp = blockIdx.y;
  const int b = bh >> 4, h = bh & 15;
  const int w = threadIdx.x >> 6, lane = threadIdx.x & 63;
  const int lr = lane & 15, lg = lane >> 4;
  const float slope = exp2f(-0.5f * (float)(h + 1));
  const __hip_bfloat16* Kbase = QKV + (size_t)b * Tc * NQ + Cc + h * Dc;
  const __hip_bfloat16* Vbase = Vt + (size_t)bh * Dc * Tc;
  const int krow = (lane >> 4);
  const int kcolb = ((lane & 15) << 4);
  const int vrow = (lane >> 3);
  const int vcolb = ((lane & 7) << 4);
  f32x4 zero = {0.f, 0.f, 0.f, 0.f};

#define STAGE(bb, t)                                                              \
    {                                                                             \
      const int s0_ = (t) * 64;                                                   \
      for (int j = 0; j < 4; j++) {                                               \
        int row = w * 16 + j * 4 + krow;                                          \
        int cb = kcolb ^ ((row & 7) << 4);                                        \
        gload16(Kbase + (size_t)(s0_ + row) * NQ + (cb >> 1),                     \
                &Ks[bb][w * 16 + j * 4][0]);                                      \
      }                                                                           \
      for (int j = 0; j < 4; j++) {                                               \
        int row = w * 32 + j * 8 + vrow;                                          \
        int cb = vcolb ^ ((row & 7) << 4);                                        \
        gload16(Vbase + (size_t)row * Tc + s0_ + (cb >> 1),                       \
                &Vs[bb][w * 32 + j * 8][0]);                                      \
      }                                                                           \
    }
#define SBAR asm volatile("s_barrier" ::: "memory")
#define AVW8 asm volatile("s_waitcnt vmcnt(8)" ::: "memory")
#define AVW0 asm volatile("s_waitcnt vmcnt(0)" ::: "memory")
#define ALG0 asm volatile("s_waitcnt lgkmcnt(0)" ::: "memory")

  int buf = 0;
  for (int ti = 0; ti < 2; ti++) {
    const int qt = (ti == 0) ? (31 - pp) : pp;
    const int q0 = qt * 64 + w * 16;
    const int nchunk = qt + 1;
    bf16x8 aq[4];
    {
      const __hip_bfloat16* qb = QKV + (size_t)(b * Tc + q0 + lr) * NQ + h * Dc + lg * 8;
      for (int c = 0; c < 4; c++) aq[c] = *(const bf16x8*)(qb + c * 32);
    }
    f32x4 acc[8];
    for (int d = 0; d < 8; d++) acc[d] = zero;
    float mrow[4] = {-1e30f, -1e30f, -1e30f, -1e30f};
    float lsum[4] = {0.f, 0.f, 0.f, 0.f};   // per-lane partial

    SBAR;                    // protect K/V buffers vs previous q-tile readers
    STAGE(buf, 0);
    for (int t = 0; t < nchunk; t++) {
      if (t + 1 < nchunk) { STAGE(buf ^ 1, t + 1); AVW8; }
      else                { AVW0; }
      SBAR;
      const int s0 = t * 64;
      // ---- QK^T (16 MFMA) ----
      f32x4 s[4];
      for (int ss = 0; ss < 4; ss++) s[ss] = zero;
      __builtin_amdgcn_s_setprio(1);
      for (int c = 0; c < 4; c++)
        for (int ss = 0; ss < 4; ss++) {
          int kr = ss * 16 + lr;
          const bf16x8 kf = *(const bf16x8*)
              &Ks[buf][kr][((c * 64 + lg * 16) ^ ((kr & 7) << 4)) >> 1];
          s[ss] = mfma16(aq[c], kf, s[ss]);
        }
      __builtin_amdgcn_s_setprio(0);
      // ---- softmax (online, r7 math; full-chunk fast path) ----
      const bool full = (s0 + 63 <= q0);
      float ps[4][4], mt[4];
      for (int r = 0; r < 4; r++) mt[r] = -1e30f;
      if (full) {
        for (int ss = 0; ss < 4; ss++) {
          int jj = s0 + ss * 16 + lr;
          for (int r = 0; r < 4; r++) {
            int i = q0 + lg * 4 + r;
            float pv = s[ss][r] - slope * (float)(i - jj);
            ps[ss][r] = pv;
            mt[r] = fmaxf(mt[r], pv);
          }
        }
      } else {
        for (int ss = 0; ss < 4; ss++) {
          int jj = s0 + ss * 16 + lr;
          for (int r = 0; r < 4; r++) {
            int i = q0 + lg * 4 + r;
            float pv = (jj <= i) ? s[ss][r] - slope * (float)(i - jj) : -1e30f;
            ps[ss][r] = pv;
            mt[r] = fmaxf(mt[r], pv);
          }
        }
      }
      for (int m = 1; m < 16; m <<= 1)
        for (int r = 0; r < 4; r++) mt[r] = fmaxf(mt[r], __shfl_xor(mt[r], m));
      float corr[4];
      for (int r = 0; r < 4; r++) {
        float mn = fmaxf(mrow[r], mt[r]);
        corr[r] = __expf(mrow[r] - mn);
        mrow[r] = mn;
      }
      for (int r = 0; r < 4; r++) lsum[r] *= corr[r];
      for (int ss = 0; ss < 4; ss++)
        for (int r = 0; r < 4; r++) {
          float e = __expf(ps[ss][r] - mrow[r]);
          ps[ss][r] = e;
          lsum[r] += e;
        }
      for (int d = 0; d < 8; d++)
        for (int r = 0; r < 4; r++) acc[d][r] *= corr[r];
      // ---- P -> LDS, PV (16 MFMA) ----
      for (int ss = 0; ss < 4; ss++)
        for (int r = 0; r < 4; r++)
          Plds[w][lg * 4 + r][ss * 16 + lr] = __float2bfloat16(ps[ss][r]);
      bf16x8 pa0 = *(const bf16x8*)&Plds[w][lr][lg * 8];
      bf16x8 pa1 = *(const bf16x8*)&Plds[w][lr][32 + lg * 8];
      __builtin_amdgcn_s_setprio(1);
      for (int d = 0; d < 8; d++) {
        int vr = d * 16 + lr;
        const bf16x8 b0 = *(const bf16x8*)
            &Vs[buf][vr][((lg * 16) ^ ((vr & 7) << 4)) >> 1];
        const bf16x8 b1 = *(const bf16x8*)
            &Vs[buf][vr][((64 + lg * 16) ^ ((vr & 7) << 4)) >> 1];
        acc[d] = mfma16(pa0, b0, acc[d]);
        acc[d] = mfma16(pa1, b1, acc[d]);
      }
      __builtin_amdgcn_s_setprio(0);
      ALG0; SBAR;            // reads of buf done before next overwrite
      buf ^= 1;
    }
    // ---- epilogue: reduce lsum (deferred), 1/l, subln rmsnorm, store ----
    for (int m = 1; m < 16; m <<= 1)
      for (int r = 0; r < 4; r++) lsum[r] += __shfl_xor(lsum[r], m);
    float ssum[4] = {0.f, 0.f, 0.f, 0.f};
    for (int r = 0; r < 4; r++) {
      float rl = 1.0f / lsum[r];
      for (int d = 0; d < 8; d++) {
        float o = acc[d][r] * rl;
        acc[d][r] = o;
        ssum[r] += o * o;
      }
    }
    for (int m = 1; m < 16; m <<= 1)
      for (int r = 0; r < 4; r++) ssum[r] += __shfl_xor(ssum[r], m);
    float ms[4];
    for (int r = 0; r < 4; r++) ms[r] = rsqrtf(ssum[r] * (1.0f / Dc) + EPSc);
    for (int d = 0; d < 8; d++) {
      float wv = subw[d * 16 + lr];
      for (int r = 0; r < 4; r++) {
        float y = acc[d][r] * ms[r] * wv;
        Y[(size_t)(b * Tc + q0 + lg * 4 + r) * Cc + h * Dc + d * 16 + lr] =
            __float2bfloat16(y);
      }
    }
  }
#undef STAGE
#undef SBAR
#undef AVW8
#undef AVW0
#undef ALG0
}

extern "C" void kernel_launch(void* const* d_in, const int* in_sizes, int n_in,
                              void* d_out, int out_size, void* d_ws, size_t ws_size,
                              hipStream_t stream) {
  const float* x  = (const float*)d_in[0];
  const float* Wq = (const float*)d_in[1];
  const float* Wk = (const float*)d_in[2];
  const float* Wv = (const float*)d_in[3];
  const float* Wp = (const float*)d_in[4];
  const float* qw = (const float*)d_in[5];
  const float* kw = (const float*)d_in[6];
  const float* sw = (const float*)d_in[7];
  float* out = (float*)d_out;

  char* ws = (char*)d_ws;
  __hip_bfloat16* Xb    = (__hip_bfloat16*)(ws + 0);          // 16 MiB (4096x2048)
  __hip_bfloat16* Wqkv  = (__hip_bfloat16*)(ws + 16777216);   // 24 MiB (6144x2048, N-major)
  __hip_bfloat16* Wproj = (__hip_bfloat16*)(ws + 41943040);   //  8 MiB (2048x2048, N-major)
  __hip_bfloat16* QKV   = (__hip_bfloat16*)(ws + 50331648);   // 48 MiB (4096x6144)
  __hip_bfloat16* Vt    = (__hip_bfloat16*)(ws + 100663296);  // 16 MiB (b,h,d,t)
  __hip_bfloat16* Yb    = (__hip_bfloat16*)(ws + 117440512);  // 16 MiB (4096x2048)

  k_xconv<<<dim3((BTc * Cc) / 1024), 256, 0, stream>>>(x, Xb);
  k_wconv<<<dim3(32, 32, 4), 256, 0, stream>>>(Wq, Wk, Wv, Wp, Wqkv, Wproj);
  // QKV GEMM (128x128 tiles, 3 blocks/CU) with fused QK-RMSNorm and
  // V-transpose; grid 32x48 = 1536 wgs = 6/CU exact
  k_gemmf<1, __hip_bfloat16><<<dim3((BTc / 128) * (NQ / 128)), 256, 0, stream>>>(
      Xb, Wqkv, QKV, BTc, NQ, qw, kw, Vt);
  k_attn<<<dim3(Bc * Hc, 16), 256, 0, stream>>>(QKV, Vt, sw, Yb);
  // proj: plain mode, grid 32x16 = 512 wgs = 2/CU exact
  k_gemmf<0, float><<<dim3((BTc / 128) * (Cc / 128)), 256, 0, stream>>>(
      Yb, Wproj, out, BTc, Cc, nullptr, nullptr, nullptr);
}

// Round 17
// 250.737 us; speedup vs baseline: 1.1305x; 1.1305x over previous
//
#include <hip/hip_runtime.h>
#include <hip/hip_bf16.h>

// Problem constants
#define Bc 2
#define Tc 2048
#define Cc 2048
#define Hc 16
#define Dc 128
#define BTc 4096
#define NQ 6144            // 3*Cc
#define EPSc 1e-5f
#define QSCALE 0.08838834764831845f   // 1/sqrt(128)

typedef __attribute__((ext_vector_type(8))) short bf16x8;
typedef __attribute__((ext_vector_type(4))) short bf16x4;
typedef __attribute__((ext_vector_type(4))) float f32x4;

typedef struct { unsigned short u[4]; } us4;

__device__ __forceinline__ f32x4 mfma16(bf16x8 a, bf16x8 b, f32x4 c) {
  return __builtin_amdgcn_mfma_f32_16x16x32_bf16(a, b, c, 0, 0, 0);
}

__device__ __forceinline__ void gload16(const void* g, void* l) {
  __builtin_amdgcn_global_load_lds(
      (const __attribute__((address_space(1))) void*)g,
      (__attribute__((address_space(3))) void*)l, 16, 0, 0);
}

// ------- merged prep: weight transpose+convert (z<4) + x convert (z==4) ----
// z<4: W (K x N) fp32 -> Wt (N x K) bf16 via 64x65-padded LDS tile,
//      float4 loads (16B/lane), 8B transposed stores.
// z==4: x fp32 -> bf16, 8192 elements per block (float4 grid-stride).
__global__ __launch_bounds__(256) void k_prep(const float* __restrict__ Wq,
    const float* __restrict__ Wk, const float* __restrict__ Wv,
    const float* __restrict__ Wp, __hip_bfloat16* __restrict__ Wqkv_t,
    __hip_bfloat16* __restrict__ Wproj_t,
    const float* __restrict__ x, __hip_bfloat16* __restrict__ xb) {
  int z = blockIdx.z;
  if (z == 4) {
    // xconv slice: 32x32 blocks x 8192 elements = 4096x2048
    size_t b4 = (size_t)blockIdx.y * 32 + blockIdx.x;
    size_t base = b4 * 8192 + threadIdx.x * 4;
#pragma unroll
    for (int j = 0; j < 8; j++) {
      size_t i = base + (size_t)j * 1024;
      float4 v = *(const float4*)(x + i);
      union { __hip_bfloat16 h[4]; bf16x4 v4; } u;
      u.h[0] = __float2bfloat16(v.x); u.h[1] = __float2bfloat16(v.y);
      u.h[2] = __float2bfloat16(v.z); u.h[3] = __float2bfloat16(v.w);
      *(bf16x4*)(xb + i) = u.v4;
    }
    return;
  }
  __shared__ float tile[64][65];
  const float* src = (z == 0) ? Wq : (z == 1) ? Wk : (z == 2) ? Wv : Wp;
  __hip_bfloat16* dst = (z < 3) ? (Wqkv_t + (size_t)z * Cc * Cc) : Wproj_t;
  int k0 = blockIdx.x * 64, n0 = blockIdx.y * 64;
  int l16 = threadIdx.x & 15, rg = threadIdx.x >> 4;   // 16 lanes/row, 16 rows
#pragma unroll
  for (int p = 0; p < 4; p++) {
    int r = p * 16 + rg;
    float4 v = *(const float4*)(src + (size_t)(k0 + r) * Cc + n0 + l16 * 4);
    tile[r][l16 * 4 + 0] = v.x; tile[r][l16 * 4 + 1] = v.y;
    tile[r][l16 * 4 + 2] = v.z; tile[r][l16 * 4 + 3] = v.w;
  }
  __syncthreads();
#pragma unroll
  for (int p = 0; p < 4; p++) {
    int rn = p * 16 + rg;
    int ck = l16 * 4;
    union { us4 s; unsigned long long q; } u;
#pragma unroll
    for (int j = 0; j < 4; j++) {
      union { __hip_bfloat16 h; unsigned short v; } cv;
      cv.h = __float2bfloat16(tile[ck + j][rn]);
      u.s.u[j] = cv.v;
    }
    *(unsigned long long*)(dst + (size_t)(n0 + rn) * Cc + k0 + ck) = u.q;
  }
}

// ============ 128x256-tile GEMM, 4 waves of 64x128, BK=32, ring-3 ==========
// (best known: ~114us QKV, MfmaUtil ~40%, 900 TF-class)
// MODE 0: plain (OutT out, row-major).  MODE 1 (QKV fused): region by>>3:
//   0 -> Q: rmsnorm(fp32 acc) * qw * QSCALE -> QKV
//   1 -> K: rmsnorm * kw -> QKV
//   2 -> V: write transposed to Vt[(b*16+h)*128+d][t] (skip QKV)
__device__ __forceinline__ void mm48(f32x4 (&acc)[4][8], const bf16x8 (&A_)[4],
                                     const bf16x8 (&B_)[8]) {
  __builtin_amdgcn_s_setprio(1);
#pragma unroll
  for (int m = 0; m < 4; m++)
#pragma unroll
    for (int n = 0; n < 8; n++)
      acc[m][n] = mfma16(A_[m], B_[n], acc[m][n]);
  __builtin_amdgcn_s_setprio(0);
}

template <int MODE, typename OutT>
__global__ __launch_bounds__(256, 2) void k_gemm4(const __hip_bfloat16* __restrict__ A,
    const __hip_bfloat16* __restrict__ Bt, OutT* __restrict__ Co,
    int M, int N, const float* __restrict__ qw, const float* __restrict__ kw,
    __hip_bfloat16* __restrict__ Vt) {
  constexpr int K = 2048;
  __shared__ __align__(16) char lds[73728];            // 3 x 24KB ring
  const int nbx = M >> 7;                               // 128-row tiles
  const int nwg = nbx * (N >> 8);                       // %8==0
  const int wg = blockIdx.x;
  const int swz = (wg & 7) * (nwg >> 3) + (wg >> 3);
  const int bx = swz % nbx, by = swz / nbx;
  const int tid = threadIdx.x, lane = tid & 63, wid = tid >> 6;
  const int wr = wid >> 1, wc = wid & 1;
  const int lr = lane & 15, lg = lane >> 4;
  const int xs = lg ^ ((lr >> 1) & 3);
  const int aoffR = (wr * 64 + lr) * 64 + xs * 16;         // + m*1024 + buf
  const int boffR = 8192 + (wc * 128 + lr) * 64 + xs * 16; // + n*1024 + buf
  const int srow = lane >> 2;
  const int scolE = (((lane & 3) ^ ((lane >> 3) & 3)) << 3);
  const __hip_bfloat16* Ag = A + (size_t)(bx * 128 + wid * 32 + srow) * K + scolE;
  const __hip_bfloat16* Bg = Bt + (size_t)(by * 256 + wid * 64 + srow) * K + scolE;
  const size_t rK16 = (size_t)16 * K;
  char* dA = lds + wid * 2048;          // + buf*24576 (+j*1024)
  char* dB = lds + 8192 + wid * 4096;   // + buf*24576 (+j*1024)

#define STG(BUF, TS) {                                                   \
    gload16(Ag + (TS) * 32,        dA + (BUF) * 24576);                  \
    gload16(Ag + rK16 + (TS) * 32, dA + (BUF) * 24576 + 1024);           \
    gload16(Bg + (TS) * 32,            dB + (BUF) * 24576);              \
    gload16(Bg + rK16 + (TS) * 32,     dB + (BUF) * 24576 + 1024);       \
    gload16(Bg + 2 * rK16 + (TS) * 32, dB + (BUF) * 24576 + 2048);       \
    gload16(Bg + 3 * rK16 + (TS) * 32, dB + (BUF) * 24576 + 3072);       \
  }
#define BARRIER asm volatile("s_barrier" ::: "memory")
#define VW6 asm volatile("s_waitcnt vmcnt(6)" ::: "memory")
#define VW0 asm volatile("s_waitcnt vmcnt(0)" ::: "memory")

  f32x4 acc[4][8];
#pragma unroll
  for (int m = 0; m < 4; m++)
#pragma unroll
    for (int n = 0; n < 8; n++) acc[m][n] = f32x4{0.f, 0.f, 0.f, 0.f};
  bf16x8 rA[4], rB[8];

#define PH(RB, SB, TS, DOSTG, ENDW) {                                    \
    _Pragma("unroll")                                                    \
    for (int m = 0; m < 4; m++)                                          \
      rA[m] = *(const bf16x8*)(lds + (RB) * 24576 + aoffR + m * 1024);   \
    _Pragma("unroll")                                                    \
    for (int n = 0; n < 8; n++)                                          \
      rB[n] = *(const bf16x8*)(lds + (RB) * 24576 + boffR + n * 1024);   \
    if (DOSTG) STG((SB), (TS));                                          \
    mm48(acc, rA, rB);                                                   \
    ENDW;                                                                \
    BARRIER;                                                             \
  }

  // prologue: stage tiles 0,1 into bufs 0,1; tile0 landed at VW6
  STG(0, 0); STG(1, 1);
  VW6;
  BARRIER;

  for (int i = 0; i < 20; ++i) {
    const int t = 3 * i;
    PH(0, 2, t + 2, 1, VW6);    // tile 3i
    PH(1, 0, t + 3, 1, VW6);    // tile 3i+1
    PH(2, 1, t + 4, 1, VW6);    // tile 3i+2
  }
  PH(0, 2, 62, 1, VW6);         // t=60
  PH(1, 0, 63, 1, VW6);         // t=61
  PH(2, 0, 0, 0, VW0);          // t=62 (drain tile 63)
  PH(0, 0, 0, 0, (void)0);      // t=63
#undef PH
#undef STG
#undef BARRIER
#undef VW6
#undef VW0

  const int row0 = bx * 128 + wr * 64 + lg * 4;
  const int col0 = by * 256 + wc * 128 + lr;

  if (MODE == 1) {
    const int region = by >> 3;            // 0=Q, 1=K, 2=V
    if (region < 2) {
      const float* wsel = (region == 0) ? qw : kw;
      const float extra = (region == 0) ? QSCALE : 1.0f;
      float wv[8];
#pragma unroll
      for (int n = 0; n < 8; n++) wv[n] = wsel[n * 16 + lr];
#pragma unroll
      for (int m = 0; m < 4; m++) {
        float ss[4] = {0.f, 0.f, 0.f, 0.f};
#pragma unroll
        for (int n = 0; n < 8; n++)
#pragma unroll
          for (int r = 0; r < 4; r++) ss[r] += acc[m][n][r] * acc[m][n][r];
        for (int msk = 1; msk < 16; msk <<= 1)
#pragma unroll
          for (int r = 0; r < 4; r++) ss[r] += __shfl_xor(ss[r], msk);
        float sc[4];
#pragma unroll
        for (int r = 0; r < 4; r++)
          sc[r] = rsqrtf(ss[r] * (1.0f / Dc) + EPSc) * extra;
#pragma unroll
        for (int n = 0; n < 8; n++) {
          size_t base = (size_t)(row0 + m * 16) * N + col0 + n * 16;
#pragma unroll
          for (int r = 0; r < 4; r++)
            ((__hip_bfloat16*)Co)[base + (size_t)r * N] =
                __float2bfloat16(acc[m][n][r] * sc[r] * wv[n]);
        }
      }
    } else {
      // V: write transposed to Vt[(b*16+h)*128 + d][t]
      const int h = ((by - 16) * 256 + wc * 128) >> 7;   // 0..15
      const int bat = bx >> 4;                            // batch (rows/2048)
#pragma unroll
      for (int m = 0; m < 4; m++) {
        const int t0 = (row0 + m * 16) & (Tc - 1);
#pragma unroll
        for (int n = 0; n < 8; n++) {
          union { us4 p; unsigned long long q; } u;
#pragma unroll
          for (int r = 0; r < 4; r++) {
            union { __hip_bfloat16 h16; unsigned short s; } cv;
            cv.h16 = __float2bfloat16(acc[m][n][r]);
            u.p.u[r] = cv.s;
          }
          __hip_bfloat16* dst = Vt +
              ((size_t)(bat * 16 + h) * 128 + n * 16 + lr) * Tc + t0;
          *(unsigned long long*)dst = u.q;
        }
      }
    }
  } else {
#pragma unroll
    for (int m = 0; m < 4; m++)
#pragma unroll
      for (int n = 0; n < 8; n++) {
        size_t base = (size_t)(row0 + m * 16) * N + col0 + n * 16;
#pragma unroll
        for (int r = 0; r < 4; r++) {
          float v = acc[m][n][r];
          if constexpr (sizeof(OutT) == 2)
            Co[base + (size_t)r * N] = __float2bfloat16(v);
          else
            Co[base + (size_t)r * N] = v;
        }
      }
  }
}

// ---------------- flash attention: counted-vmcnt pipeline, r7 softmax ------
// + deferred l-sum (epilogue reduce) + full-chunk fast path (both verified).
__global__ __launch_bounds__(256, 2) void k_attn(const __hip_bfloat16* __restrict__ QKV,
    const __hip_bfloat16* __restrict__ Vt, const float* __restrict__ subw,
    __hip_bfloat16* __restrict__ Y) {
  __shared__ __align__(16) __hip_bfloat16 Ks[2][64][128];   // 32 KB
  __shared__ __align__(16) __hip_bfloat16 Vs[2][128][64];   // 32 KB
  __shared__ __align__(16) __hip_bfloat16 Plds[4][16][72];  // 9 KB
  const int bh = blockIdx.x, pp = blockIdx.y;
  const int b = bh >> 4, h = bh & 15;
  const int w = threadIdx.x >> 6, lane = threadIdx.x & 63;
  const int lr = lane & 15, lg = lane >> 4;
  const float slope = exp2f(-0.5f * (float)(h + 1));
  const __hip_bfloat16* Kbase = QKV + (size_t)b * Tc * NQ + Cc + h * Dc;
  const __hip_bfloat16* Vbase = Vt + (size_t)bh * Dc * Tc;
  const int krow = (lane >> 4);
  const int kcolb = ((lane & 15) << 4);
  const int vrow = (lane >> 3);
  const int vcolb = ((lane & 7) << 4);
  f32x4 zero = {0.f, 0.f, 0.f, 0.f};

#define STAGE(bb, t)                                                              \
    {                                                                             \
      const int s0_ = (t) * 64;                                                   \
      for (int j = 0; j < 4; j++) {                                               \
        int row = w * 16 + j * 4 + krow;                                          \
        int cb = kcolb ^ ((row & 7) << 4);                                        \
        gload16(Kbase + (size_t)(s0_ + row) * NQ + (cb >> 1),                     \
                &Ks[bb][w * 16 + j * 4][0]);                                      \
      }                                                                           \
      for (int j = 0; j < 4; j++) {                                               \
        int row = w * 32 + j * 8 + vrow;                                          \
        int cb = vcolb ^ ((row & 7) << 4);                                        \
        gload16(Vbase + (size_t)row * Tc + s0_ + (cb >> 1),                       \
                &Vs[bb][w * 32 + j * 8][0]);                                      \
      }                                                                           \
    }
#define SBAR asm volatile("s_barrier" ::: "memory")
#define AVW8 asm volatile("s_waitcnt vmcnt(8)" ::: "memory")
#define AVW0 asm volatile("s_waitcnt vmcnt(0)" ::: "memory")
#define ALG0 asm volatile("s_waitcnt lgkmcnt(0)" ::: "memory")

  int buf = 0;
  for (int ti = 0; ti < 2; ti++) {
    const int qt = (ti == 0) ? (31 - pp) : pp;
    const int q0 = qt * 64 + w * 16;
    const int nchunk = qt + 1;
    bf16x8 aq[4];
    {
      const __hip_bfloat16* qb = QKV + (size_t)(b * Tc + q0 + lr) * NQ + h * Dc + lg * 8;
      for (int c = 0; c < 4; c++) aq[c] = *(const bf16x8*)(qb + c * 32);
    }
    f32x4 acc[8];
    for (int d = 0; d < 8; d++) acc[d] = zero;
    float mrow[4] = {-1e30f, -1e30f, -1e30f, -1e30f};
    float lsum[4] = {0.f, 0.f, 0.f, 0.f};   // per-lane partial

    SBAR;                    // protect K/V buffers vs previous q-tile readers
    STAGE(buf, 0);
    for (int t = 0; t < nchunk; t++) {
      if (t + 1 < nchunk) { STAGE(buf ^ 1, t + 1); AVW8; }
      else                { AVW0; }
      SBAR;
      const int s0 = t * 64;
      // ---- QK^T (16 MFMA) ----
      f32x4 s[4];
      for (int ss = 0; ss < 4; ss++) s[ss] = zero;
      __builtin_amdgcn_s_setprio(1);
      for (int c = 0; c < 4; c++)
        for (int ss = 0; ss < 4; ss++) {
          int kr = ss * 16 + lr;
          const bf16x8 kf = *(const bf16x8*)
              &Ks[buf][kr][((c * 64 + lg * 16) ^ ((kr & 7) << 4)) >> 1];
          s[ss] = mfma16(aq[c], kf, s[ss]);
        }
      __builtin_amdgcn_s_setprio(0);
      // ---- softmax (online, r7 math; full-chunk fast path) ----
      const bool full = (s0 + 63 <= q0);
      float ps[4][4], mt[4];
      for (int r = 0; r < 4; r++) mt[r] = -1e30f;
      if (full) {
        for (int ss = 0; ss < 4; ss++) {
          int jj = s0 + ss * 16 + lr;
          for (int r = 0; r < 4; r++) {
            int i = q0 + lg * 4 + r;
            float pv = s[ss][r] - slope * (float)(i - jj);
            ps[ss][r] = pv;
            mt[r] = fmaxf(mt[r], pv);
          }
        }
      } else {
        for (int ss = 0; ss < 4; ss++) {
          int jj = s0 + ss * 16 + lr;
          for (int r = 0; r < 4; r++) {
            int i = q0 + lg * 4 + r;
            float pv = (jj <= i) ? s[ss][r] - slope * (float)(i - jj) : -1e30f;
            ps[ss][r] = pv;
            mt[r] = fmaxf(mt[r], pv);
          }
        }
      }
      for (int m = 1; m < 16; m <<= 1)
        for (int r = 0; r < 4; r++) mt[r] = fmaxf(mt[r], __shfl_xor(mt[r], m));
      float corr[4];
      for (int r = 0; r < 4; r++) {
        float mn = fmaxf(mrow[r], mt[r]);
        corr[r] = __expf(mrow[r] - mn);
        mrow[r] = mn;
      }
      for (int r = 0; r < 4; r++) lsum[r] *= corr[r];
      for (int ss = 0; ss < 4; ss++)
        for (int r = 0; r < 4; r++) {
          float e = __expf(ps[ss][r] - mrow[r]);
          ps[ss][r] = e;
          lsum[r] += e;
        }
      for (int d = 0; d < 8; d++)
        for (int r = 0; r < 4; r++) acc[d][r] *= corr[r];
      // ---- P -> LDS, PV (16 MFMA) ----
      for (int ss = 0; ss < 4; ss++)
        for (int r = 0; r < 4; r++)
          Plds[w][lg * 4 + r][ss * 16 + lr] = __float2bfloat16(ps[ss][r]);
      bf16x8 pa0 = *(const bf16x8*)&Plds[w][lr][lg * 8];
      bf16x8 pa1 = *(const bf16x8*)&Plds[w][lr][32 + lg * 8];
      __builtin_amdgcn_s_setprio(1);
      for (int d = 0; d < 8; d++) {
        int vr = d * 16 + lr;
        const bf16x8 b0 = *(const bf16x8*)
            &Vs[buf][vr][((lg * 16) ^ ((vr & 7) << 4)) >> 1];
        const bf16x8 b1 = *(const bf16x8*)
            &Vs[buf][vr][((64 + lg * 16) ^ ((vr & 7) << 4)) >> 1];
        acc[d] = mfma16(pa0, b0, acc[d]);
        acc[d] = mfma16(pa1, b1, acc[d]);
      }
      __builtin_amdgcn_s_setprio(0);
      ALG0; SBAR;            // reads of buf done before next overwrite
      buf ^= 1;
    }
    // ---- epilogue: reduce lsum (deferred), 1/l, subln rmsnorm, store ----
    for (int m = 1; m < 16; m <<= 1)
      for (int r = 0; r < 4; r++) lsum[r] += __shfl_xor(lsum[r], m);
    float ssum[4] = {0.f, 0.f, 0.f, 0.f};
    for (int r = 0; r < 4; r++) {
      float rl = 1.0f / lsum[r];
      for (int d = 0; d < 8; d++) {
        float o = acc[d][r] * rl;
        acc[d][r] = o;
        ssum[r] += o * o;
      }
    }
    for (int m = 1; m < 16; m <<= 1)
      for (int r = 0; r < 4; r++) ssum[r] += __shfl_xor(ssum[r], m);
    float ms[4];
    for (int r = 0; r < 4; r++) ms[r] = rsqrtf(ssum[r] * (1.0f / Dc) + EPSc);
    for (int d = 0; d < 8; d++) {
      float wv = subw[d * 16 + lr];
      for (int r = 0; r < 4; r++) {
        float y = acc[d][r] * ms[r] * wv;
        Y[(size_t)(b * Tc + q0 + lg * 4 + r) * Cc + h * Dc + d * 16 + lr] =
            __float2bfloat16(y);
      }
    }
  }
#undef STAGE
#undef SBAR
#undef AVW8
#undef AVW0
#undef ALG0
}

extern "C" void kernel_launch(void* const* d_in, const int* in_sizes, int n_in,
                              void* d_out, int out_size, void* d_ws, size_t ws_size,
                              hipStream_t stream) {
  const float* x  = (const float*)d_in[0];
  const float* Wq = (const float*)d_in[1];
  const float* Wk = (const float*)d_in[2];
  const float* Wv = (const float*)d_in[3];
  const float* Wp = (const float*)d_in[4];
  const float* qw = (const float*)d_in[5];
  const float* kw = (const float*)d_in[6];
  const float* sw = (const float*)d_in[7];
  float* out = (float*)d_out;

  char* ws = (char*)d_ws;
  __hip_bfloat16* Xb    = (__hip_bfloat16*)(ws + 0);          // 16 MiB (4096x2048)
  __hip_bfloat16* Wqkv  = (__hip_bfloat16*)(ws + 16777216);   // 24 MiB (6144x2048, N-major)
  __hip_bfloat16* Wproj = (__hip_bfloat16*)(ws + 41943040);   //  8 MiB (2048x2048, N-major)
  __hip_bfloat16* QKV   = (__hip_bfloat16*)(ws + 50331648);   // 48 MiB (4096x6144)
  __hip_bfloat16* Vt    = (__hip_bfloat16*)(ws + 100663296);  // 16 MiB (b,h,d,t)
  __hip_bfloat16* Yb    = (__hip_bfloat16*)(ws + 117440512);  // 16 MiB (4096x2048)

  // merged prep: z<4 weight transpose, z==4 x convert
  k_prep<<<dim3(32, 32, 5), 256, 0, stream>>>(Wq, Wk, Wv, Wp, Wqkv, Wproj, x, Xb);
  // QKV GEMM with fused QK-RMSNorm (+QSCALE) and V-transpose; 768 wgs
  k_gemm4<1, __hip_bfloat16><<<dim3((BTc / 128) * (NQ / 256)), 256, 0, stream>>>(
      Xb, Wqkv, QKV, BTc, NQ, qw, kw, Vt);
  k_attn<<<dim3(Bc * Hc, 16), 256, 0, stream>>>(QKV, Vt, sw, Yb);
  // proj: plain mode, 256 wgs
  k_gemm4<0, float><<<dim3((BTc / 128) * (Cc / 256)), 256, 0, stream>>>(
      Yb, Wproj, out, BTc, Cc, nullptr, nullptr, nullptr);
}